// Round 10
// baseline (446.560 us; speedup 1.0000x reference)
//
#include <hip/hip_runtime.h>
#include <math.h>

// ---------------------------------------------------------------------------
// Dual CTC loss forward — single fused producer/consumer kernel (R10).
//  error task:   B=32, T=2000, C=4,  S=50   (P=1 pair/lane)
//  phoneme task: B=32, T=2000, C=64, S=200  (P=4 pairs/lane)
// Per block (256 thr): wave 3 = consumer running the beta-normalized B/L
// fp64 recursion (R8-validated); waves 0-2 = producers turning raw logits
// into expanded ratio rows r_s = exp2((z_{tgt[s]}-z_0)*log2e) in a
// double-buffered 16-row LDS ring, plus log2(pb) per row into LDS.
// No intermediate global G buffer, no separate gather dispatch: kills both
// R8's gather time and most of the multi-launch overhead floor.
// Consumer reads are conflict-free ds_read_b128 (R9's raw-row class-gather
// conflicts, 430k, proved expansion must stay off the serial path).
// ---------------------------------------------------------------------------

static constexpr float  LOG2E = 1.4426950408889634f;
static constexpr double LN2D  = 0.6931471805599453;

#define DPP_WAVE_SHR1   0x138
#define DPP_ROW_SHR(n)  (0x110 | (n))
#define DPP_ROW_BCAST15 0x142
#define DPP_ROW_BCAST31 0x143

__device__ __forceinline__ float fexp2(float x) {
  return __builtin_amdgcn_exp2f(x);
}
__device__ __forceinline__ float flog2(float x) {
  return __builtin_amdgcn_logf(x);
}

// prev-lane value (lane i gets lane i-1; lane 0 gets 0.0) — pure VALU
__device__ __forceinline__ double dpp_shr1_f64(double x) {
  int lo = __double2loint(x), hi = __double2hiint(x);
  lo = __builtin_amdgcn_update_dpp(0, lo, DPP_WAVE_SHR1, 0xf, 0xf, true);
  hi = __builtin_amdgcn_update_dpp(0, hi, DPP_WAVE_SHR1, 0xf, 0xf, true);
  return __hiloint2double(hi, lo);
}

__device__ __forceinline__ int imax2(int a, int b) { return a > b ? a : b; }

__device__ __forceinline__ int wave_imax(int v) {
  v = imax2(v, __builtin_amdgcn_update_dpp(0, v, DPP_ROW_SHR(1), 0xf, 0xf, true));
  v = imax2(v, __builtin_amdgcn_update_dpp(0, v, DPP_ROW_SHR(2), 0xf, 0xf, true));
  v = imax2(v, __builtin_amdgcn_update_dpp(0, v, DPP_ROW_SHR(4), 0xf, 0xf, true));
  v = imax2(v, __builtin_amdgcn_update_dpp(0, v, DPP_ROW_SHR(8), 0xf, 0xf, true));
  v = imax2(v, __builtin_amdgcn_update_dpp(0, v, DPP_ROW_BCAST15, 0xf, 0xf, true));
  v = imax2(v, __builtin_amdgcn_update_dpp(0, v, DPP_ROW_BCAST31, 0xf, 0xf, true));
  return __builtin_amdgcn_readlane(v, 63);
}

template <int P> struct RowP { float v[P]; };

template <int P>
__device__ __forceinline__ RowP<P> lread(const float* p) {
  RowP<P> r;
  if constexpr (P == 4) {
    const float4 a = *(const float4*)p;
    r.v[0] = a.x; r.v[1] = a.y; r.v[2] = a.z; r.v[3] = a.w;
  } else {
    r.v[0] = *p;
  }
  return r;
}

template <int P>
__device__ __forceinline__ void bl_renorm(double (&B)[P], double (&L)[P],
                                          int& K) {
  double mm = B[0];
#pragma unroll
  for (int k = 0; k < P; ++k) mm = fmax(fmax(mm, B[k]), L[k]);
  const int ex = (__double2hiint(mm) >> 20) & 0x7ff;
  const int emax = wave_imax(ex);
  if (emax > 0) {
    int d = 1523 - emax;            // pin band max to ~2^500 (R4..R8-proven)
    if (d > 1023) d = 1023;
    if (d < -1022) d = -1022;
    const double sc = __hiloint2double((d + 1023) << 20, 0);
#pragma unroll
    for (int k = 0; k < P; ++k) { B[k] *= sc; L[k] *= sc; }
    K += d;
  }
}

template <int P>
__device__ __forceinline__ void bl_step(double (&B)[P], double (&L)[P],
                                        const double (&skipm)[P],
                                        const RowP<P>& f) {
  const double Lm1 = dpp_shr1_f64(L[P - 1]);
  double nB[P], nL[P];
#pragma unroll
  for (int k = 0; k < P; ++k) {
    const double Lp = (k >= 1) ? L[k - 1] : Lm1;
    nB[k] = B[k] + Lp;
    nL[k] = (double)f.v[k] * fma(skipm[k], Lp, B[k] + L[k]);
  }
#pragma unroll
  for (int k = 0; k < P; ++k) { B[k] = nB[k]; L[k] = nL[k]; }
}

// ---------------------------------------------------------------------------
// One block = one chain. wave 3 consumes; waves 0-2 produce.
template <int P, int S, bool PH>
__device__ __forceinline__ void fused_chain(
    const float* __restrict__ logits,  // [2000][C] raw logits, C = PH?64:4
    const int* __restrict__ tb,        // [S]
    int len, int tl, float* __restrict__ out,
    float* ring,   // 2 groups x 16 rows x 64*P floats
    float* lpb,    // [2048] log2(pb(t))
    double* sa) {  // [512] readout
  constexpr int RS = 64 * P;  // floats per expanded row
  const int wid = threadIdx.x >> 6;
  const int lane = threadIdx.x & 63;

  // per-lane class slots (s = lane*P + k), used by producers (PH bpermute
  // indices / error select) — and masks for dead slots
  int cls[P];
  float mask[P];
#pragma unroll
  for (int k = 0; k < P; ++k) {
    const int s = lane * P + k;
    cls[k] = (s < S) ? tb[s] : 0;
    mask[k] = (s < S) ? 1.0f : 0.0f;
  }

  // ---- consumer state + prologue (runs while producers prime group 0) ----
  double skipm[P], B[P], L[P];
  int K = 0;
  if (wid == 3) {
#pragma unroll
    for (int k = 0; k < P; ++k) {
      const int s = lane * P + k;
      skipm[k] = (s >= 1 && s < S && tb[s] != tb[s - 1]) ? 1.0 : 0.0;
      B[k] = 0.0;
      L[k] = 0.0;
    }
    if constexpr (PH) {
      const float z = logits[lane];
      const float z0 =
          __int_as_float(__builtin_amdgcn_readfirstlane(__float_as_int(z)));
      float s = fexp2((z - z0) * LOG2E);
#pragma unroll
      for (int off = 32; off >= 1; off >>= 1) s += __shfl_xor(s, off, 64);
      if (lane == 0) {
        lpb[0] = -flog2(s);
        B[0] = 1.0;
        L[0] = (double)fexp2((logits[tb[0]] - logits[0]) * LOG2E);
      }
    } else {
      if (lane == 0) {
        const float4 v = *(const float4*)logits;
        const float r1 = fexp2((v.y - v.x) * LOG2E);
        const float r2 = fexp2((v.z - v.x) * LOG2E);
        const float r3 = fexp2((v.w - v.x) * LOG2E);
        lpb[0] = -flog2(1.0f + r1 + r2 + r3);
        B[0] = 1.0;
        const int c = tb[0];
        L[0] = (double)((c == 1) ? r1 : (c == 2) ? r2 : r3);
      }
    }
  }

  // ---- producer: one expanded ratio row ----
  auto produce_row = [&](int t, float* dst) {
    if constexpr (PH) {
      const float z = logits[(size_t)t * 64 + lane];
      const float z0 =
          __int_as_float(__builtin_amdgcn_readfirstlane(__float_as_int(z)));
      const float r = fexp2((z - z0) * LOG2E);
      float s = r;
#pragma unroll
      for (int off = 32; off >= 1; off >>= 1) s += __shfl_xor(s, off, 64);
      const int ri = __float_as_int(r);
      float4 o;
      o.x = __int_as_float(__builtin_amdgcn_ds_bpermute(cls[0] << 2, ri)) * mask[0];
      o.y = __int_as_float(__builtin_amdgcn_ds_bpermute(cls[1] << 2, ri)) * mask[1];
      o.z = __int_as_float(__builtin_amdgcn_ds_bpermute(cls[2] << 2, ri)) * mask[2];
      o.w = __int_as_float(__builtin_amdgcn_ds_bpermute(cls[3] << 2, ri)) * mask[3];
      *(float4*)(dst + lane * 4) = o;
      if (lane == 0) lpb[t] = -flog2(s);
    } else {
      const float4 v = *(const float4*)(logits + (size_t)t * 4);
      const float r1 = fexp2((v.y - v.x) * LOG2E);
      const float r2 = fexp2((v.z - v.x) * LOG2E);
      const float r3 = fexp2((v.w - v.x) * LOG2E);
      const int c = cls[0];
      dst[lane] = ((c == 1) ? r1 : (c == 2) ? r2 : r3) * mask[0];
      if (lane == 0) lpb[t] = -flog2(1.0f + r1 + r2 + r3);
    }
  };
  auto produce_group = [&](int g) {
    const int cnt = min(16, len - 1 - g * 16);
    float* lb = ring + (g & 1) * 16 * RS;
    for (int u = wid; u < cnt; u += 3)
      produce_row(1 + g * 16 + u, lb + u * RS);
  };

  const int ntot = (len - 1 + 15) >> 4;  // groups of 16 t-steps

  if (wid < 3 && ntot > 0) produce_group(0);
  __syncthreads();

  for (int g = 0; g < ntot; ++g) {
    if (wid == 3) {
      bl_renorm<P>(B, L, K);  // every 16 steps
      const int cnt = min(16, len - 1 - g * 16);
      const float* lb = ring + (g & 1) * 16 * RS + lane * P;
      if (cnt == 16) {
        RowP<P> c0 = lread<P>(lb);
        RowP<P> c1 = lread<P>(lb + RS);
        RowP<P> c2 = lread<P>(lb + 2 * RS);
        RowP<P> c3 = lread<P>(lb + 3 * RS);
#pragma unroll
        for (int u = 0; u < 16; ++u) {
          RowP<P> cn = c3;
          if (u + 4 < 16) cn = lread<P>(lb + (u + 4) * RS);
          bl_step<P>(B, L, skipm, c0);
          c0 = c1; c1 = c2; c2 = c3; c3 = cn;
        }
      } else {
        for (int u = 0; u < cnt; ++u) {
          const RowP<P> f = lread<P>(lb + u * RS);
          bl_step<P>(B, L, skipm, f);
        }
      }
    } else {
      if (g + 1 < ntot) produce_group(g + 1);
    }
    __syncthreads();
  }

  // ---- epilogue ----
  float spb = 0.f;
  if (wid == 3) {
    for (int t = lane; t < len; t += 64) spb += lpb[t];
#pragma unroll
    for (int off = 32; off >= 1; off >>= 1) spb += __shfl_xor(spb, off, 64);
#pragma unroll
    for (int k = 0; k < P; ++k) {
      sa[lane * P + k] = B[k];            // B block: sa[0 .. 64P)
      sa[64 * P + lane * P + k] = L[k];   // L block: sa[64P .. 128P)
    }
  }
  __syncthreads();
  if (wid == 3 && lane == 0) {
    const double a = sa[64 * P + (tl - 1)] + sa[tl];  // L[tl-1] + B[tl]
    float loss = (float)((double)K * LN2D - log(a) - (double)spb * LN2D);
    if (!(loss < 1e29f)) loss = 0.f;  // zero_infinity
    atomicAdd(out, loss / ((float)tl * 32.0f));
  }
}

__global__ __launch_bounds__(256) void ctc_fused_kernel(
    const float* __restrict__ err_logits, const float* __restrict__ ph_logits,
    const int* __restrict__ err_tgt, const int* __restrict__ ph_tgt,
    const int* __restrict__ err_il, const int* __restrict__ ph_il,
    const int* __restrict__ err_tl, const int* __restrict__ ph_tl,
    float* __restrict__ out) {
  __shared__ float ring[2 * 16 * 256];  // 32 KB
  __shared__ float lpb[2048];           // 8 KB
  __shared__ double sa[512];            // 4 KB
  const int blk = blockIdx.x;
  if (blk < 32) {
    int len = err_il[blk];
    if (len > 2000) len = 2000;
    fused_chain<1, 50, false>(err_logits + (size_t)blk * 2000 * 4,
                              err_tgt + blk * 50, len, err_tl[blk], out, ring,
                              lpb, sa);
  } else {
    const int b = blk - 32;
    int len = ph_il[b];
    if (len > 2000) len = 2000;
    fused_chain<4, 200, true>(ph_logits + (size_t)b * 2000 * 64,
                              ph_tgt + b * 200, len, ph_tl[b], out, ring, lpb,
                              sa);
  }
}

// ========================= launch ==========================================

extern "C" void kernel_launch(void* const* d_in, const int* in_sizes, int n_in,
                              void* d_out, int out_size, void* d_ws,
                              size_t ws_size, hipStream_t stream) {
  const float* err_logits = (const float*)d_in[0];
  const float* ph_logits  = (const float*)d_in[1];
  const int* err_tgt = (const int*)d_in[2];
  const int* ph_tgt  = (const int*)d_in[3];
  const int* err_il  = (const int*)d_in[4];
  const int* ph_il   = (const int*)d_in[5];
  const int* err_tl  = (const int*)d_in[6];
  const int* ph_tl   = (const int*)d_in[7];
  float* out = (float*)d_out;

  (void)hipMemsetAsync(d_out, 0, sizeof(float), stream);
  ctc_fused_kernel<<<64, 256, 0, stream>>>(err_logits, ph_logits, err_tgt,
                                           ph_tgt, err_il, ph_il, err_tl,
                                           ph_tl, out);
}

// Round 11
// 332.243 us; speedup vs baseline: 1.3441x; 1.3441x over previous
//
#include <hip/hip_runtime.h>
#include <math.h>

// ---------------------------------------------------------------------------
// Dual CTC loss forward — single fused producer/consumer kernel (R11).
//  error task:   B=32, T=2000, C=4,  S=50   (P=1 pair/lane)
//  phoneme task: B=32, T=2000, C=64, S=200  (P=4 pairs/lane)
// Per block (256 thr): wave 3 = consumer (beta-normalized B/L fp64 recursion,
// R8-validated); waves 0-2 = producers (logits -> expanded ratio rows in LDS).
// R11 fixes R10's producer serialization (420us, ~6000cy/group):
//  - producers load their <=6 rows into a STATIC register array first
//    (independent loads batched in flight), then reduce/bpermute/write;
//  - triple-buffered 16-row ring: produce group g+2 while consuming g
//    (one full group of latency slack).
// Consumer reads stay conflict-free ds_read_b128 (R9's 430k-conflict lesson).
// ---------------------------------------------------------------------------

static constexpr float  LOG2E = 1.4426950408889634f;
static constexpr double LN2D  = 0.6931471805599453;

#define DPP_WAVE_SHR1   0x138
#define DPP_ROW_SHR(n)  (0x110 | (n))
#define DPP_ROW_BCAST15 0x142
#define DPP_ROW_BCAST31 0x143

__device__ __forceinline__ float fexp2(float x) {
  return __builtin_amdgcn_exp2f(x);
}
__device__ __forceinline__ float flog2(float x) {
  return __builtin_amdgcn_logf(x);
}

__device__ __forceinline__ double dpp_shr1_f64(double x) {
  int lo = __double2loint(x), hi = __double2hiint(x);
  lo = __builtin_amdgcn_update_dpp(0, lo, DPP_WAVE_SHR1, 0xf, 0xf, true);
  hi = __builtin_amdgcn_update_dpp(0, hi, DPP_WAVE_SHR1, 0xf, 0xf, true);
  return __hiloint2double(hi, lo);
}

__device__ __forceinline__ int imax2(int a, int b) { return a > b ? a : b; }

__device__ __forceinline__ int wave_imax(int v) {
  v = imax2(v, __builtin_amdgcn_update_dpp(0, v, DPP_ROW_SHR(1), 0xf, 0xf, true));
  v = imax2(v, __builtin_amdgcn_update_dpp(0, v, DPP_ROW_SHR(2), 0xf, 0xf, true));
  v = imax2(v, __builtin_amdgcn_update_dpp(0, v, DPP_ROW_SHR(4), 0xf, 0xf, true));
  v = imax2(v, __builtin_amdgcn_update_dpp(0, v, DPP_ROW_SHR(8), 0xf, 0xf, true));
  v = imax2(v, __builtin_amdgcn_update_dpp(0, v, DPP_ROW_BCAST15, 0xf, 0xf, true));
  v = imax2(v, __builtin_amdgcn_update_dpp(0, v, DPP_ROW_BCAST31, 0xf, 0xf, true));
  return __builtin_amdgcn_readlane(v, 63);
}

template <int P> struct RowP { float v[P]; };

template <int P>
__device__ __forceinline__ RowP<P> lread(const float* p) {
  RowP<P> r;
  if constexpr (P == 4) {
    const float4 a = *(const float4*)p;
    r.v[0] = a.x; r.v[1] = a.y; r.v[2] = a.z; r.v[3] = a.w;
  } else {
    r.v[0] = *p;
  }
  return r;
}

template <int P>
__device__ __forceinline__ void bl_renorm(double (&B)[P], double (&L)[P],
                                          int& K) {
  double mm = B[0];
#pragma unroll
  for (int k = 0; k < P; ++k) mm = fmax(fmax(mm, B[k]), L[k]);
  const int ex = (__double2hiint(mm) >> 20) & 0x7ff;
  const int emax = wave_imax(ex);
  if (emax > 0) {
    int d = 1523 - emax;            // pin band max to ~2^500 (R4..R8-proven)
    if (d > 1023) d = 1023;
    if (d < -1022) d = -1022;
    const double sc = __hiloint2double((d + 1023) << 20, 0);
#pragma unroll
    for (int k = 0; k < P; ++k) { B[k] *= sc; L[k] *= sc; }
    K += d;
  }
}

template <int P>
__device__ __forceinline__ void bl_step(double (&B)[P], double (&L)[P],
                                        const double (&skipm)[P],
                                        const RowP<P>& f) {
  const double Lm1 = dpp_shr1_f64(L[P - 1]);
  double nB[P], nL[P];
#pragma unroll
  for (int k = 0; k < P; ++k) {
    const double Lp = (k >= 1) ? L[k - 1] : Lm1;
    nB[k] = B[k] + Lp;
    nL[k] = (double)f.v[k] * fma(skipm[k], Lp, B[k] + L[k]);
  }
#pragma unroll
  for (int k = 0; k < P; ++k) { B[k] = nB[k]; L[k] = nL[k]; }
}

// ---------------------------------------------------------------------------
// One block = one chain. wave 3 consumes; waves 0-2 produce.
template <int P, int S, bool PH>
__device__ __forceinline__ void fused_chain(
    const float* __restrict__ logits,  // [2000][C] raw logits, C = PH?64:4
    const int* __restrict__ tb,        // [S]
    int len, int tl, float* __restrict__ out,
    float* ring,   // 3 slots x 16 rows x 64*P floats
    float* lpb,    // [2048] log2(pb(t))
    double* sa) {  // [512] readout
  constexpr int RS = 64 * P;         // floats per expanded row
  constexpr int SLOT = 16 * RS;      // floats per ring slot
  const int wid = threadIdx.x >> 6;
  const int lane = threadIdx.x & 63;

  int cls[P];
  float mask[P];
#pragma unroll
  for (int k = 0; k < P; ++k) {
    const int s = lane * P + k;
    cls[k] = (s < S) ? tb[s] : 0;
    mask[k] = (s < S) ? 1.0f : 0.0f;
  }

  // ---- consumer state + t=0 prologue (R10-validated) ----
  double skipm[P], B[P], L[P];
  int K = 0;
  if (wid == 3) {
#pragma unroll
    for (int k = 0; k < P; ++k) {
      const int s = lane * P + k;
      skipm[k] = (s >= 1 && s < S && tb[s] != tb[s - 1]) ? 1.0 : 0.0;
      B[k] = 0.0;
      L[k] = 0.0;
    }
    if constexpr (PH) {
      const float z = logits[lane];
      const float z0 =
          __int_as_float(__builtin_amdgcn_readfirstlane(__float_as_int(z)));
      float s = fexp2((z - z0) * LOG2E);
#pragma unroll
      for (int off = 32; off >= 1; off >>= 1) s += __shfl_xor(s, off, 64);
      if (lane == 0) {
        lpb[0] = -flog2(s);
        B[0] = 1.0;
        L[0] = (double)fexp2((logits[tb[0]] - logits[0]) * LOG2E);
      }
    } else {
      if (lane == 0) {
        const float4 v = *(const float4*)logits;
        const float r1 = fexp2((v.y - v.x) * LOG2E);
        const float r2 = fexp2((v.z - v.x) * LOG2E);
        const float r3 = fexp2((v.w - v.x) * LOG2E);
        lpb[0] = -flog2(1.0f + r1 + r2 + r3);
        B[0] = 1.0;
        const int c = tb[0];
        L[0] = (double)((c == 1) ? r1 : (c == 2) ? r2 : r3);
      }
    }
  }

  // ---- producer: one 16-row group into ring slot. Loads batched first
  //      (static unroll, independent loads in flight), then process. ----
  auto produce_group = [&](int g, int slot) {
    const int t0 = 1 + g * 16;
    const int cnt = min(16, len - t0);
    float* lb = ring + slot * SLOT;
    if constexpr (PH) {
      float z[6];
#pragma unroll
      for (int i = 0; i < 6; ++i) {
        const int u = wid + 3 * i;
        if (u < cnt) z[i] = logits[(size_t)(t0 + u) * 64 + lane];
      }
#pragma unroll
      for (int i = 0; i < 6; ++i) {
        const int u = wid + 3 * i;
        if (u < cnt) {
          const float zz = z[i];
          const float z0 = __int_as_float(
              __builtin_amdgcn_readfirstlane(__float_as_int(zz)));
          const float r = fexp2((zz - z0) * LOG2E);
          float s = r;
#pragma unroll
          for (int off = 32; off >= 1; off >>= 1) s += __shfl_xor(s, off, 64);
          const int ri = __float_as_int(r);
          float4 o;
          o.x = __int_as_float(__builtin_amdgcn_ds_bpermute(cls[0] << 2, ri)) * mask[0];
          o.y = __int_as_float(__builtin_amdgcn_ds_bpermute(cls[1] << 2, ri)) * mask[1];
          o.z = __int_as_float(__builtin_amdgcn_ds_bpermute(cls[2] << 2, ri)) * mask[2];
          o.w = __int_as_float(__builtin_amdgcn_ds_bpermute(cls[3] << 2, ri)) * mask[3];
          *(float4*)(lb + u * RS + lane * 4) = o;
          if (lane == 0) lpb[t0 + u] = -flog2(s);
        }
      }
    } else {
      float4 v[6];
#pragma unroll
      for (int i = 0; i < 6; ++i) {
        const int u = wid + 3 * i;
        if (u < cnt) v[i] = *(const float4*)(logits + (size_t)(t0 + u) * 4);
      }
#pragma unroll
      for (int i = 0; i < 6; ++i) {
        const int u = wid + 3 * i;
        if (u < cnt) {
          const float r1 = fexp2((v[i].y - v[i].x) * LOG2E);
          const float r2 = fexp2((v[i].z - v[i].x) * LOG2E);
          const float r3 = fexp2((v[i].w - v[i].x) * LOG2E);
          const int c = cls[0];
          lb[u * RS + lane] = ((c == 1) ? r1 : (c == 2) ? r2 : r3) * mask[0];
          if (lane == 0) lpb[t0 + u] = -flog2(1.0f + r1 + r2 + r3);
        }
      }
    }
  };

  const int ntot = (len - 1 + 15) >> 4;  // groups of 16 t-steps

  // prime slots 0 and 1 (groups 0,1)
  if (wid < 3) {
    if (ntot > 0) produce_group(0, 0);
    if (ntot > 1) produce_group(1, 1);
  }
  __syncthreads();

  int cs = 0;  // consumer slot for group g
  int ps = 2;  // producer slot for group g+2
  for (int g = 0; g < ntot; ++g) {
    if (wid == 3) {
      bl_renorm<P>(B, L, K);  // every 16 steps
      const int cnt = min(16, len - 1 - g * 16);
      const float* lb = ring + cs * SLOT + lane * P;
      if (cnt == 16) {
        RowP<P> c0 = lread<P>(lb);
        RowP<P> c1 = lread<P>(lb + RS);
        RowP<P> c2 = lread<P>(lb + 2 * RS);
        RowP<P> c3 = lread<P>(lb + 3 * RS);
#pragma unroll
        for (int u = 0; u < 16; ++u) {
          RowP<P> cn = c3;
          if (u + 4 < 16) cn = lread<P>(lb + (u + 4) * RS);
          bl_step<P>(B, L, skipm, c0);
          c0 = c1; c1 = c2; c2 = c3; c3 = cn;
        }
      } else {
        for (int u = 0; u < cnt; ++u) {
          const RowP<P> f = lread<P>(lb + u * RS);
          bl_step<P>(B, L, skipm, f);
        }
      }
    } else {
      if (g + 2 < ntot) produce_group(g + 2, ps);
    }
    cs = (cs == 2) ? 0 : cs + 1;
    ps = (ps == 2) ? 0 : ps + 1;
    __syncthreads();
  }

  // ---- epilogue ----
  float spb = 0.f;
  if (wid == 3) {
    for (int t = lane; t < len; t += 64) spb += lpb[t];
#pragma unroll
    for (int off = 32; off >= 1; off >>= 1) spb += __shfl_xor(spb, off, 64);
#pragma unroll
    for (int k = 0; k < P; ++k) {
      sa[lane * P + k] = B[k];            // B block: sa[0 .. 64P)
      sa[64 * P + lane * P + k] = L[k];   // L block: sa[64P .. 128P)
    }
  }
  __syncthreads();
  if (wid == 3 && lane == 0) {
    const double a = sa[64 * P + (tl - 1)] + sa[tl];  // L[tl-1] + B[tl]
    float loss = (float)((double)K * LN2D - log(a) - (double)spb * LN2D);
    if (!(loss < 1e29f)) loss = 0.f;  // zero_infinity
    atomicAdd(out, loss / ((float)tl * 32.0f));
  }
}

__global__ __launch_bounds__(256) void ctc_fused_kernel(
    const float* __restrict__ err_logits, const float* __restrict__ ph_logits,
    const int* __restrict__ err_tgt, const int* __restrict__ ph_tgt,
    const int* __restrict__ err_il, const int* __restrict__ ph_il,
    const int* __restrict__ err_tl, const int* __restrict__ ph_tl,
    float* __restrict__ out) {
  __shared__ float ring[3 * 16 * 256];  // 48 KB
  __shared__ float lpb[2048];           // 8 KB
  __shared__ double sa[512];            // 4 KB
  const int blk = blockIdx.x;
  if (blk < 32) {
    int len = err_il[blk];
    if (len > 2000) len = 2000;
    fused_chain<1, 50, false>(err_logits + (size_t)blk * 2000 * 4,
                              err_tgt + blk * 50, len, err_tl[blk], out, ring,
                              lpb, sa);
  } else {
    const int b = blk - 32;
    int len = ph_il[b];
    if (len > 2000) len = 2000;
    fused_chain<4, 200, true>(ph_logits + (size_t)b * 2000 * 64,
                              ph_tgt + b * 200, len, ph_tl[b], out, ring, lpb,
                              sa);
  }
}

// ========================= launch ==========================================

extern "C" void kernel_launch(void* const* d_in, const int* in_sizes, int n_in,
                              void* d_out, int out_size, void* d_ws,
                              size_t ws_size, hipStream_t stream) {
  const float* err_logits = (const float*)d_in[0];
  const float* ph_logits  = (const float*)d_in[1];
  const int* err_tgt = (const int*)d_in[2];
  const int* ph_tgt  = (const int*)d_in[3];
  const int* err_il  = (const int*)d_in[4];
  const int* ph_il   = (const int*)d_in[5];
  const int* err_tl  = (const int*)d_in[6];
  const int* ph_tl   = (const int*)d_in[7];
  float* out = (float*)d_out;

  (void)hipMemsetAsync(d_out, 0, sizeof(float), stream);
  ctc_fused_kernel<<<64, 256, 0, stream>>>(err_logits, ph_logits, err_tgt,
                                           ph_tgt, err_il, ph_il, err_tl,
                                           ph_tl, out);
}

// Round 12
// 276.532 us; speedup vs baseline: 1.6149x; 1.2015x over previous
//
#include <hip/hip_runtime.h>
#include <math.h>

// ---------------------------------------------------------------------------
// Dual CTC loss forward (R12): R8 decoupled structure + 2-wave band split.
//  error task:   B=32, T=2000, C=4,  S=50   (wave A owns all live pairs)
//  phoneme task: B=32, T=2000, C=64, S=200  (A: pairs 0..127, B: 128..200)
// Gather kernel (R8-validated): expanded ratio rows r_s = p_{tgt[s]}/p_blank
// into G (s-ordered), log2(pb) into Lpb. Chain kernel: 2 waves per block.
// CTC dependencies flow low-s -> high-s only, so wave B runs one 16-step
// window BEHIND wave A, consuming A's per-step boundary L[127] values frozen
// in an LDS ring (rescaled across the waves' independent renorm frames via
// exponent arithmetic). One barrier per 16 steps. DMA: global_load_lds rows
// into a 4-slot LDS ring (R8-proven vmcnt discipline, wave A issues).
// Readout: per-half K, combined with f64 logaddexp.
// Falls back to the R2 proven path if ws too small.
// ---------------------------------------------------------------------------

static constexpr float  LOG2E = 1.4426950408889634f;
static constexpr double LN2D  = 0.6931471805599453;
static constexpr int GROWS = 2032;  // padded rows per chain (DMA overrun pad)

#define DPP_WAVE_SHR1   0x138
#define DPP_ROW_SHR(n)  (0x110 | (n))
#define DPP_ROW_BCAST15 0x142
#define DPP_ROW_BCAST31 0x143

__device__ __forceinline__ float fexp2(float x) {
  return __builtin_amdgcn_exp2f(x);
}
__device__ __forceinline__ float flog2(float x) {
  return __builtin_amdgcn_logf(x);
}

// prev-lane value within a wave (lane 0 gets 0.0) — pure VALU
__device__ __forceinline__ double dpp_shr1_f64(double x) {
  int lo = __double2loint(x), hi = __double2hiint(x);
  lo = __builtin_amdgcn_update_dpp(0, lo, DPP_WAVE_SHR1, 0xf, 0xf, true);
  hi = __builtin_amdgcn_update_dpp(0, hi, DPP_WAVE_SHR1, 0xf, 0xf, true);
  return __hiloint2double(hi, lo);
}

__device__ __forceinline__ int imax2(int a, int b) { return a > b ? a : b; }

__device__ __forceinline__ int wave_imax(int v) {
  v = imax2(v, __builtin_amdgcn_update_dpp(0, v, DPP_ROW_SHR(1), 0xf, 0xf, true));
  v = imax2(v, __builtin_amdgcn_update_dpp(0, v, DPP_ROW_SHR(2), 0xf, 0xf, true));
  v = imax2(v, __builtin_amdgcn_update_dpp(0, v, DPP_ROW_SHR(4), 0xf, 0xf, true));
  v = imax2(v, __builtin_amdgcn_update_dpp(0, v, DPP_ROW_SHR(8), 0xf, 0xf, true));
  v = imax2(v, __builtin_amdgcn_update_dpp(0, v, DPP_ROW_BCAST15, 0xf, 0xf, true));
  v = imax2(v, __builtin_amdgcn_update_dpp(0, v, DPP_ROW_BCAST31, 0xf, 0xf, true));
  return __builtin_amdgcn_readlane(v, 63);
}

// async global->LDS DMA (literal size immediates; vmcnt-tracked)
__device__ __forceinline__ void dma4(const float* g, float* l) {
  __builtin_amdgcn_global_load_lds((const __attribute__((address_space(1))) void*)g,
                                   (__attribute__((address_space(3))) void*)l,
                                   4, 0, 0);
}
__device__ __forceinline__ void dma16(const float* g, float* l) {
  __builtin_amdgcn_global_load_lds((const __attribute__((address_space(1))) void*)g,
                                   (__attribute__((address_space(3))) void*)l,
                                   16, 0, 0);
}

// s_waitcnt with literal simm16 (vmcnt[3:0]=b3:0, exp=b6:4, lgkm=b11:8)
__device__ __forceinline__ void wait_vmcnt16() {
  __builtin_amdgcn_sched_barrier(0);
  __builtin_amdgcn_s_waitcnt(20336);  // vmcnt=16, exp=7, lgkm=15
  __builtin_amdgcn_sched_barrier(0);
}
__device__ __forceinline__ void wait_vmcnt0() {
  __builtin_amdgcn_sched_barrier(0);
  __builtin_amdgcn_s_waitcnt(3952);   // vmcnt=0, exp=7, lgkm=15
  __builtin_amdgcn_sched_barrier(0);
}

// ========================= gather (R8-validated) ===========================

__global__ __launch_bounds__(256) void gather_all_kernel(
    const float* __restrict__ ph_logits, const float* __restrict__ err_logits,
    const int* __restrict__ ph_tgt, const int* __restrict__ err_tgt,
    float* __restrict__ Gph, float* __restrict__ Ger,
    float* __restrict__ Lpb_ph, float* __restrict__ Lpb_er) {
  const int lane = threadIdx.x & 63;
  const int t = blockIdx.x * 4 + (threadIdx.x >> 6);
  const int b = blockIdx.y;
  if (blockIdx.z == 0) {
    const float z = ph_logits[((size_t)b * 2000 + t) * 64 + lane] * LOG2E;
    float m = z;
#pragma unroll
    for (int off = 32; off >= 1; off >>= 1) m = fmaxf(m, __shfl_xor(m, off, 64));
    const float zm = z - m;
    const float e = fexp2(zm);
    float s = e;
#pragma unroll
    for (int off = 32; off >= 1; off >>= 1) s += __shfl_xor(s, off, 64);
    const int ei = __float_as_int(e);
    const float e0 = __int_as_float(__builtin_amdgcn_readlane(ei, 0));
    const float inv0 = 1.0f / e0;  // r = e_cls / e_blank
    const int* tb = ph_tgt + b * 200;
    float o[4];
#pragma unroll
    for (int k = 0; k < 4; ++k) {
      const int si = lane * 4 + k;
      const int cls = (si < 200) ? tb[si] : 0;
      const float v = __int_as_float(__builtin_amdgcn_ds_bpermute(cls << 2, ei));
      o[k] = (si < 200) ? (v * inv0) : 0.0f;
    }
    *(float4*)(Gph + ((size_t)b * GROWS + t) * 256 + lane * 4) =
        make_float4(o[0], o[1], o[2], o[3]);
    if (lane == 0)
      Lpb_ph[(size_t)b * GROWS + t] = zm - flog2(s);  // log2(pb)
  } else {
    const float4 v = *(const float4*)(err_logits + ((size_t)b * 2000 + t) * 4);
    const float z0 = v.x * LOG2E, z1 = v.y * LOG2E, z2 = v.z * LOG2E,
                z3 = v.w * LOG2E;
    const float m = fmaxf(fmaxf(z0, z1), fmaxf(z2, z3));
    const float e0 = fexp2(z0 - m), e1 = fexp2(z1 - m);
    const float e2 = fexp2(z2 - m), e3 = fexp2(z3 - m);
    const int c1 = err_tgt[b * 50 + (lane < 50 ? lane : 49)];
    const float num = (c1 == 1) ? e1 : (c1 == 2) ? e2 : e3;
    Ger[((size_t)b * GROWS + t) * 64 + lane] = (lane < 50) ? (num / e0) : 0.0f;
    if (lane == 0)
      Lpb_er[(size_t)b * GROWS + t] = (z0 - m) - flog2(e0 + e1 + e2 + e3);
  }
}

// ========================= chain (2-wave split) ============================

template <int P> struct RowP { float v[P]; };

template <int P>
__device__ __forceinline__ RowP<P> lread(const float* p) {
  RowP<P> r;
  if constexpr (P == 2) {
    const float2 a = *(const float2*)p;
    r.v[0] = a.x;
    r.v[1] = a.y;
  } else {
    r.v[0] = *p;
  }
  return r;
}

// returns emax (0 => this wave's half is entirely zero)
template <int P>
__device__ __forceinline__ int bl_renorm(double (&B)[P], double (&L)[P],
                                         int& K) {
  double mm = B[0];
#pragma unroll
  for (int k = 0; k < P; ++k) mm = fmax(fmax(mm, B[k]), L[k]);
  const int ex = (__double2hiint(mm) >> 20) & 0x7ff;
  const int emax = wave_imax(ex);
  if (emax > 0) {
    int d = 1523 - emax;            // pin band max to ~2^500 (R4..R8-proven)
    if (d > 1023) d = 1023;
    if (d < -1022) d = -1022;
    const double sc = __hiloint2double((d + 1023) << 20, 0);
#pragma unroll
    for (int k = 0; k < P; ++k) { B[k] *= sc; L[k] *= sc; }
    K += d;
  }
  return emax;
}

// one recursion step; lane0's cross-boundary L value = bndv (wave A: 0.0)
template <int P>
__device__ __forceinline__ void bl_step(double (&B)[P], double (&L)[P],
                                        const double (&skipm)[P],
                                        const RowP<P>& f, double bndv,
                                        int lane) {
  double Lm1 = dpp_shr1_f64(L[P - 1]);
  if (lane == 0) Lm1 = bndv;
  double nB[P], nL[P];
#pragma unroll
  for (int k = 0; k < P; ++k) {
    const double Lp = (k >= 1) ? L[k - 1] : Lm1;
    nB[k] = B[k] + Lp;
    nL[k] = (double)f.v[k] * fma(skipm[k], Lp, B[k] + L[k]);
  }
#pragma unroll
  for (int k = 0; k < P; ++k) { B[k] = nB[k]; L[k] = nL[k]; }
}

// One block (128 thr = 2 waves) advances one chain.
// Wave A owns pairs 0..64P-1; wave B owns 64P..128P-1 (masked past S).
template <int P, int S, int RSF, bool PH>
__device__ __forceinline__ void split_chain(
    const float* __restrict__ G,    // [GROWS][RSF] expanded ratio rows
    const float* __restrict__ Lpb,  // [GROWS] log2(pb)
    const int* __restrict__ tb, int len, int tl, float* __restrict__ out,
    float* ring, double* bnd, int* kexs, double* saB, double* saL,
    int* kfin) {
  constexpr int SLOT = 16 * RSF;
  constexpr int HALF = 64 * P;                 // pairs per wave
  constexpr bool BDEAD = (HALF >= S + 1);      // wave B half entirely dead
  const int wid = threadIdx.x >> 6;
  const int lane = threadIdx.x & 63;
  const int off = wid ? HALF : 0;

  // spb = sum_{t<len} log2(pb(t))  (wave A)
  float spb = 0.f;
  if (wid == 0) {
    for (int t = lane; t < len; t += 64) spb += Lpb[t];
#pragma unroll
    for (int o = 32; o >= 1; o >>= 1) spb += __shfl_xor(spb, o, 64);
  }

  double skipm[P], B[P], L[P];
#pragma unroll
  for (int k = 0; k < P; ++k) {
    const int s = off + lane * P + k;
    skipm[k] = (s >= 1 && s < S && tb[s] != tb[s - 1]) ? 1.0 : 0.0;
    B[k] = 0.0;
    L[k] = 0.0;
  }
  int K = 0;
  if (wid == 0 && lane == 0) {
    B[0] = 1.0;         // beta-normalized: B[0] = pb/pb = 1
    L[0] = (double)G[0];  // r_{tgt[0]}(t=0) (expanded row 0, slot 0)
  }

  const int ntot = (len - 1 + 15) >> 4;  // 16-step windows

  auto issue = [&](int w) {  // wave A only
    const float* rb = G + (size_t)(1 + w * 16) * RSF + lane * (PH ? 4 : 1);
    float* lb = ring + (w & 3) * SLOT;
#pragma unroll
    for (int u = 0; u < 16; ++u) {
      if constexpr (PH) dma16(rb + u * RSF, lb + u * RSF);
      else              dma4(rb + u * RSF, lb + u * RSF);
    }
  };

  if (wid == 0) {
    if (ntot > 0) issue(0);
    if (ntot > 1) issue(1);
  }

  for (int p = 0; p <= ntot; ++p) {
    if (wid == 0) {
      if (p < ntot) {
        if (p + 1 < ntot) wait_vmcnt16();  // slot p resident
        else              wait_vmcnt0();
        bl_renorm<P>(B, L, K);
        if (lane == 0) kexs[p & 1] = K;
        const int cnt = (len - 1 - p * 16 < 16) ? (len - 1 - p * 16) : 16;
        const float* lb = ring + (p & 3) * SLOT + lane * P;
        const int bb = (p & 1) * 16;
        if (cnt == 16) {
          RowP<P> c0 = lread<P>(lb);
          RowP<P> c1 = lread<P>(lb + RSF);
          RowP<P> c2 = lread<P>(lb + 2 * RSF);
          RowP<P> c3 = lread<P>(lb + 3 * RSF);
#pragma unroll
          for (int u = 0; u < 16; ++u) {
            RowP<P> cn = c3;
            if (u + 4 < 16) cn = lread<P>(lb + (u + 4) * RSF);
            if constexpr (!BDEAD)
              if (lane == 63) bnd[bb + u] = L[P - 1];  // pre-step boundary
            bl_step<P>(B, L, skipm, c0, 0.0, lane);
            c0 = c1; c1 = c2; c2 = c3; c3 = cn;
          }
        } else {
          for (int u = 0; u < cnt; ++u) {
            const RowP<P> f = lread<P>(lb + u * RSF);
            if constexpr (!BDEAD)
              if (lane == 63) bnd[bb + u] = L[P - 1];
            bl_step<P>(B, L, skipm, f, 0.0, lane);
          }
        }
        if (p + 2 < ntot) issue(p + 2);
      }
    } else if constexpr (!BDEAD) {
      if (p >= 1) {
        const int w = p - 1;
        const int emaxB = bl_renorm<P>(B, L, K);
        const int kA = kexs[w & 1];
        double adj;
        if (emaxB == 0) {  // half still empty: adopt A's frame
          K = kA;
          adj = 1.0;
        } else {
          int d = K - kA;
          if (d > 1022) d = 1022;
          if (d < -1022) d = -1022;
          adj = __hiloint2double((d + 1023) << 20, 0);
        }
        // boundary values for this window -> lanes 0..15, readlane per step
        double bv = 0.0;
        if (lane < 16) bv = bnd[(w & 1) * 16 + lane];
        const int bvlo = __double2loint(bv), bvhi = __double2hiint(bv);
        const int cnt = (len - 1 - w * 16 < 16) ? (len - 1 - w * 16) : 16;
        const float* lb = ring + (w & 3) * SLOT + HALF + lane * P;
        if (cnt == 16) {
          RowP<P> c0 = lread<P>(lb);
          RowP<P> c1 = lread<P>(lb + RSF);
          RowP<P> c2 = lread<P>(lb + 2 * RSF);
          RowP<P> c3 = lread<P>(lb + 3 * RSF);
#pragma unroll
          for (int u = 0; u < 16; ++u) {
            RowP<P> cn = c3;
            if (u + 4 < 16) cn = lread<P>(lb + (u + 4) * RSF);
            const double bndv =
                __hiloint2double(__builtin_amdgcn_readlane(bvhi, u),
                                 __builtin_amdgcn_readlane(bvlo, u)) * adj;
            bl_step<P>(B, L, skipm, c0, bndv, lane);
            c0 = c1; c1 = c2; c2 = c3; c3 = cn;
          }
        } else {
          for (int u = 0; u < cnt; ++u) {
            const RowP<P> f = lread<P>(lb + u * RSF);
            const double bndv =
                __hiloint2double(__builtin_amdgcn_readlane(bvhi, u),
                                 __builtin_amdgcn_readlane(bvlo, u)) * adj;
            bl_step<P>(B, L, skipm, f, bndv, lane);
          }
        }
      }
    }
    __syncthreads();
  }

  // ---- readout: alpha[2tl-1] = L[tl-1], alpha[2tl] = B[tl] ----
#pragma unroll
  for (int k = 0; k < P; ++k) {
    saB[off + lane * P + k] = B[k];
    saL[off + lane * P + k] = L[k];
  }
  if (lane == 0) kfin[wid] = K;
  __syncthreads();
  if (wid == 0 && lane == 0) {
    const int i1 = tl - 1, i2 = tl;
    const double Lv = saL[i1], Bv = saB[i2];
    const double K1 = (double)((i1 < HALF) ? kfin[0] : kfin[1]);
    const double K2 = (double)((i2 < HALF) ? kfin[0] : kfin[1]);
    const double u1 = log(Lv) - K1 * LN2D;  // log(0) = -inf ok
    const double u2 = log(Bv) - K2 * LN2D;
    const double mx = fmax(u1, u2);
    float loss;
    if (mx < -1e300) {
      loss = 0.f;  // both zero -> +inf loss -> zero_infinity
    } else {
      const double lse = mx + log(exp(u1 - mx) + exp(u2 - mx));
      loss = (float)(-lse - (double)spb * LN2D);
      if (!(loss < 1e29f)) loss = 0.f;
    }
    atomicAdd(out, loss / ((float)tl * 32.0f));
  }
}

__global__ __launch_bounds__(128) void ctc_chains_split_kernel(
    const float* __restrict__ Gph, const float* __restrict__ Ger,
    const float* __restrict__ Lpb_ph, const float* __restrict__ Lpb_er,
    const int* __restrict__ err_tgt, const int* __restrict__ ph_tgt,
    const int* __restrict__ err_il, const int* __restrict__ ph_il,
    const int* __restrict__ err_tl, const int* __restrict__ ph_tl,
    float* __restrict__ out) {
  __shared__ float ring[4 * 16 * 256];  // 64 KB (error uses a prefix)
  __shared__ double bnd[32];            // 2 windows x 16 boundary values
  __shared__ int kexs[2];
  __shared__ double saB[256], saL[256];
  __shared__ int kfin[2];
  const int blk = blockIdx.x;
  if (blk < 32) {
    int len = err_il[blk];
    if (len > 2000) len = 2000;
    split_chain<1, 50, 64, false>(Ger + (size_t)blk * GROWS * 64,
                                  Lpb_er + (size_t)blk * GROWS,
                                  err_tgt + blk * 50, len, err_tl[blk], out,
                                  ring, bnd, kexs, saB, saL, kfin);
  } else {
    const int b = blk - 32;
    int len = ph_il[b];
    if (len > 2000) len = 2000;
    split_chain<2, 200, 256, true>(Gph + (size_t)b * GROWS * 256,
                                   Lpb_ph + (size_t)b * GROWS,
                                   ph_tgt + b * 200, len, ph_tl[b], out, ring,
                                   bnd, kexs, saB, saL, kfin);
  }
}

// ========================= fallback path (R2, proven) ======================

__global__ __launch_bounds__(256) void softmax4_kernel(
    const float* __restrict__ x, float* __restrict__ p, int nrows) {
  int r = blockIdx.x * blockDim.x + threadIdx.x;
  if (r >= nrows) return;
  float4 v = *reinterpret_cast<const float4*>(x + (size_t)r * 4);
  float z0 = v.x * LOG2E, z1 = v.y * LOG2E, z2 = v.z * LOG2E, z3 = v.w * LOG2E;
  float m = fmaxf(fmaxf(z0, z1), fmaxf(z2, z3));
  float e0 = fexp2(z0 - m), e1 = fexp2(z1 - m);
  float e2 = fexp2(z2 - m), e3 = fexp2(z3 - m);
  float inv = 1.0f / (e0 + e1 + e2 + e3);
  float4 o;
  o.x = e0 * inv; o.y = e1 * inv; o.z = e2 * inv; o.w = e3 * inv;
  *reinterpret_cast<float4*>(p + (size_t)r * 4) = o;
}

__global__ __launch_bounds__(256) void softmax64_kernel(
    const float* __restrict__ x, float* __restrict__ p, int nrows) {
  int row = blockIdx.x * 4 + (threadIdx.x >> 6);
  int lane = threadIdx.x & 63;
  if (row >= nrows) return;
  float z = x[(size_t)row * 64 + lane] * LOG2E;
  float m = z;
#pragma unroll
  for (int off = 32; off >= 1; off >>= 1) m = fmaxf(m, __shfl_xor(m, off, 64));
  float e = fexp2(z - m);
  float s = e;
#pragma unroll
  for (int off = 32; off >= 1; off >>= 1) s += __shfl_xor(s, off, 64);
  p[(size_t)row * 64 + lane] = e * (1.0f / s);
}

template <int C, int S, int R>
__device__ __forceinline__ void ctc_chain_lin_fb(
    const float* __restrict__ p_b, const int* __restrict__ tgt_b,
    int len, int tl, float* __restrict__ out, double* sa) {
  constexpr int L = 2 * S + 1;
  const int lane = threadIdx.x;
  int idx[R];
  double skipm[R];
#pragma unroll
  for (int j = 0; j < R; ++j) {
    const int l = lane * R + j;
    int cls = 0;
    bool sk = false;
    if (l & 1) {
      const int s = (l - 1) >> 1;
      const int sc = (s < S) ? s : (S - 1);
      cls = tgt_b[sc];
      if (s >= 1 && s < S) sk = (cls != tgt_b[s - 1]);
    }
    idx[j] = cls * 4;
    skipm[j] = sk ? 1.0 : 0.0;
  }
  double alpha[R];
#pragma unroll
  for (int j = 0; j < R; ++j) {
    const int l = lane * R + j;
    alpha[j] = (l <= 1) ? (double)p_b[idx[j] >> 2] : 0.0;
  }
  int K = 0;
  const int cl = lane & (C - 1);
  float rv = p_b[(size_t)((1 < len - 1) ? 1 : (len - 1)) * C + cl];
  float pf[R];
#pragma unroll
  for (int j = 0; j < R; ++j)
    pf[j] = __int_as_float(__builtin_amdgcn_ds_bpermute(idx[j], __float_as_int(rv)));
  rv = p_b[(size_t)((2 < len - 1) ? 2 : (len - 1)) * C + cl];
  for (int t = 1; t < len; ++t) {
    if ((t & 31) == 0) {
      double m = alpha[0];
#pragma unroll
      for (int j = 1; j < R; ++j) m = fmax(m, alpha[j]);
#pragma unroll
      for (int off = 1; off < 64; off <<= 1) m = fmax(m, __shfl_xor(m, off, 64));
      const long long bits = __double_as_longlong(m);
      const int e = (int)((bits >> 52) & 0x7FF);
      if (e > 0) {
        const double sc = __longlong_as_double((long long)(2046 - e) << 52);
#pragma unroll
        for (int j = 0; j < R; ++j) alpha[j] *= sc;
        K += 1023 - e;
      }
    }
    const int tn = (t + 2 < len) ? (t + 2) : (len - 1);
    const float rvn = p_b[(size_t)tn * C + cl];
    float pfn[R];
#pragma unroll
    for (int j = 0; j < R; ++j)
      pfn[j] = __int_as_float(__builtin_amdgcn_ds_bpermute(idx[j], __float_as_int(rv)));
    double am1 = __shfl_up(alpha[R - 1], 1, 64);
    double am2 = __shfl_up(alpha[R - 2], 1, 64);
    if (lane == 0) { am1 = 0.0; am2 = 0.0; }
    double na[R];
#pragma unroll
    for (int j = 0; j < R; ++j) {
      const double a0 = alpha[j];
      const double a1 = (j >= 1) ? alpha[j - 1] : am1;
      const double a2 = (j >= 2) ? alpha[j - 2] : ((j == 1) ? am1 : am2);
      double s = a0 + a1;
      s = fma(skipm[j], a2, s);
      na[j] = (double)pf[j] * s;
    }
#pragma unroll
    for (int j = 0; j < R; ++j) alpha[j] = na[j];
#pragma unroll
    for (int j = 0; j < R; ++j) pf[j] = pfn[j];
    rv = rvn;
  }
#pragma unroll
  for (int j = 0; j < R; ++j) {
    const int l = lane * R + j;
    if (l < L) sa[l] = alpha[j];
  }
  __syncthreads();
  if (lane == 0) {
    const double a = sa[2 * tl - 1] + sa[2 * tl];
    float loss = (float)((double)K * LN2D - log(a));
    if (!(loss < 1e29f)) loss = 0.0f;
    atomicAdd(out, loss / ((float)tl * 32.0f));
  }
}

__global__ __launch_bounds__(64) void ctc_chains_fb_kernel(
    const float* __restrict__ p_err, const float* __restrict__ p_ph,
    const int* __restrict__ err_tgt, const int* __restrict__ ph_tgt,
    const int* __restrict__ err_il, const int* __restrict__ ph_il,
    const int* __restrict__ err_tl, const int* __restrict__ ph_tl,
    float* __restrict__ out) {
  __shared__ double sa[512];
  const int T = 2000;
  const int blk = blockIdx.x;
  if (blk < 32) {
    const int b = blk;
    int len = err_il[b]; if (len > T) len = T;
    ctc_chain_lin_fb<4, 50, 2>(p_err + (size_t)b * T * 4, err_tgt + b * 50, len,
                               err_tl[b], out, sa);
  } else {
    const int b = blk - 32;
    int len = ph_il[b]; if (len > T) len = T;
    ctc_chain_lin_fb<64, 200, 7>(p_ph + (size_t)b * T * 64, ph_tgt + b * 200,
                                 len, ph_tl[b], out, sa);
  }
}

// ========================= launch ==========================================

extern "C" void kernel_launch(void* const* d_in, const int* in_sizes, int n_in,
                              void* d_out, int out_size, void* d_ws,
                              size_t ws_size, hipStream_t stream) {
  const float* err_logits = (const float*)d_in[0];
  const float* ph_logits  = (const float*)d_in[1];
  const int* err_tgt = (const int*)d_in[2];
  const int* ph_tgt  = (const int*)d_in[3];
  const int* err_il  = (const int*)d_in[4];
  const int* ph_il   = (const int*)d_in[5];
  const int* err_tl  = (const int*)d_in[6];
  const int* ph_tl   = (const int*)d_in[7];
  float* out = (float*)d_out;

  const size_t gph = (size_t)32 * GROWS * 256;  // 66.6 MB
  const size_t ger = (size_t)32 * GROWS * 64;   // 16.6 MB
  const size_t lpb = (size_t)32 * GROWS;        // per task
  const size_t need = (gph + ger + 2 * lpb) * sizeof(float);

  (void)hipMemsetAsync(d_out, 0, sizeof(float), stream);

  if (ws_size >= need) {
    float* Gph = (float*)d_ws;
    float* Ger = Gph + gph;
    float* Lpb_ph = Ger + ger;
    float* Lpb_er = Lpb_ph + lpb;
    dim3 grid(500, 32, 2);
    gather_all_kernel<<<grid, 256, 0, stream>>>(ph_logits, err_logits, ph_tgt,
                                                err_tgt, Gph, Ger, Lpb_ph,
                                                Lpb_er);
    ctc_chains_split_kernel<<<64, 128, 0, stream>>>(Gph, Ger, Lpb_ph, Lpb_er,
                                                    err_tgt, ph_tgt, err_il,
                                                    ph_il, err_tl, ph_tl, out);
  } else {
    const int B = 32, T = 2000;
    const int rows = B * T;
    float* p_err = (float*)d_ws;
    float* p_ph  = p_err + (size_t)rows * 4;
    softmax4_kernel<<<(rows + 255) / 256, 256, 0, stream>>>(err_logits, p_err, rows);
    softmax64_kernel<<<(rows + 3) / 4, 256, 0, stream>>>(ph_logits, p_ph, rows);
    ctc_chains_fb_kernel<<<64, 64, 0, stream>>>(p_err, p_ph, err_tgt, ph_tgt,
                                                err_il, ph_il, err_tl, ph_tl, out);
  }
}

// Round 13
// 249.267 us; speedup vs baseline: 1.7915x; 1.1094x over previous
//
#include <hip/hip_runtime.h>
#include <math.h>

// ---------------------------------------------------------------------------
// Dual CTC loss forward (R13): R12 2-wave band split + SOFT barriers.
//  error task:   B=32, T=2000, C=4,  S=50   (wave A owns all live pairs)
//  phoneme task: B=32, T=2000, C=64, S=200  (A: pairs 0..127, B: 128..200)
// R12 was correct (absmax 0.0) but its in-loop __syncthreads lowers to
// s_waitcnt vmcnt(0) + s_barrier, draining the 2-window DMA prefetch every
// 16 steps (the documented m97 barrier-drain effect) -> 220 cy/step.
// R13 replaces it with s_waitcnt lgkmcnt(0) + raw s_barrier (sched_barrier
// fenced): DS writes (bnd/kexs) are made visible, global_load_lds prefetch
// stays in flight. Ring-slot safety comes from wave A's own vmcnt(16/0)
// waits one phase earlier, not from the barrier drain.
// Everything else is R12-identical (validated).
// ---------------------------------------------------------------------------

static constexpr float  LOG2E = 1.4426950408889634f;
static constexpr double LN2D  = 0.6931471805599453;
static constexpr int GROWS = 2032;  // padded rows per chain (DMA overrun pad)

#define DPP_WAVE_SHR1   0x138
#define DPP_ROW_SHR(n)  (0x110 | (n))
#define DPP_ROW_BCAST15 0x142
#define DPP_ROW_BCAST31 0x143

__device__ __forceinline__ float fexp2(float x) {
  return __builtin_amdgcn_exp2f(x);
}
__device__ __forceinline__ float flog2(float x) {
  return __builtin_amdgcn_logf(x);
}

// prev-lane value within a wave (lane 0 gets 0.0) — pure VALU
__device__ __forceinline__ double dpp_shr1_f64(double x) {
  int lo = __double2loint(x), hi = __double2hiint(x);
  lo = __builtin_amdgcn_update_dpp(0, lo, DPP_WAVE_SHR1, 0xf, 0xf, true);
  hi = __builtin_amdgcn_update_dpp(0, hi, DPP_WAVE_SHR1, 0xf, 0xf, true);
  return __hiloint2double(hi, lo);
}

__device__ __forceinline__ int imax2(int a, int b) { return a > b ? a : b; }

__device__ __forceinline__ int wave_imax(int v) {
  v = imax2(v, __builtin_amdgcn_update_dpp(0, v, DPP_ROW_SHR(1), 0xf, 0xf, true));
  v = imax2(v, __builtin_amdgcn_update_dpp(0, v, DPP_ROW_SHR(2), 0xf, 0xf, true));
  v = imax2(v, __builtin_amdgcn_update_dpp(0, v, DPP_ROW_SHR(4), 0xf, 0xf, true));
  v = imax2(v, __builtin_amdgcn_update_dpp(0, v, DPP_ROW_SHR(8), 0xf, 0xf, true));
  v = imax2(v, __builtin_amdgcn_update_dpp(0, v, DPP_ROW_BCAST15, 0xf, 0xf, true));
  v = imax2(v, __builtin_amdgcn_update_dpp(0, v, DPP_ROW_BCAST31, 0xf, 0xf, true));
  return __builtin_amdgcn_readlane(v, 63);
}

// async global->LDS DMA (literal size immediates; vmcnt-tracked)
__device__ __forceinline__ void dma4(const float* g, float* l) {
  __builtin_amdgcn_global_load_lds((const __attribute__((address_space(1))) void*)g,
                                   (__attribute__((address_space(3))) void*)l,
                                   4, 0, 0);
}
__device__ __forceinline__ void dma16(const float* g, float* l) {
  __builtin_amdgcn_global_load_lds((const __attribute__((address_space(1))) void*)g,
                                   (__attribute__((address_space(3))) void*)l,
                                   16, 0, 0);
}

// s_waitcnt literal simm16 (vmcnt[3:0]=b3:0, exp=b6:4, lgkm=b11:8,
// vmcnt[5:4]=b15:14)
__device__ __forceinline__ void wait_vmcnt16() {
  __builtin_amdgcn_sched_barrier(0);
  __builtin_amdgcn_s_waitcnt(20336);  // vmcnt=16, exp=7, lgkm=15
  __builtin_amdgcn_sched_barrier(0);
}
__device__ __forceinline__ void wait_vmcnt0() {
  __builtin_amdgcn_sched_barrier(0);
  __builtin_amdgcn_s_waitcnt(3952);   // vmcnt=0, exp=7, lgkm=15
  __builtin_amdgcn_sched_barrier(0);
}

// soft barrier: drain LDS (lgkm=0) but keep global_load_lds (vmcnt) alive.
// simm16 = vmcnt=63 (0xF | 3<<14), exp=7, lgkm=0 -> 0xC07F = 49279.
__device__ __forceinline__ void soft_barrier() {
  __builtin_amdgcn_sched_barrier(0);
  __builtin_amdgcn_s_waitcnt(49279);  // lgkmcnt(0), vmcnt untouched
  __builtin_amdgcn_s_barrier();
  __builtin_amdgcn_sched_barrier(0);
}

// ========================= gather (R8-validated) ===========================

__global__ __launch_bounds__(256) void gather_all_kernel(
    const float* __restrict__ ph_logits, const float* __restrict__ err_logits,
    const int* __restrict__ ph_tgt, const int* __restrict__ err_tgt,
    float* __restrict__ Gph, float* __restrict__ Ger,
    float* __restrict__ Lpb_ph, float* __restrict__ Lpb_er) {
  const int lane = threadIdx.x & 63;
  const int t = blockIdx.x * 4 + (threadIdx.x >> 6);
  const int b = blockIdx.y;
  if (blockIdx.z == 0) {
    const float z = ph_logits[((size_t)b * 2000 + t) * 64 + lane] * LOG2E;
    float m = z;
#pragma unroll
    for (int off = 32; off >= 1; off >>= 1) m = fmaxf(m, __shfl_xor(m, off, 64));
    const float zm = z - m;
    const float e = fexp2(zm);
    float s = e;
#pragma unroll
    for (int off = 32; off >= 1; off >>= 1) s += __shfl_xor(s, off, 64);
    const int ei = __float_as_int(e);
    const float e0 = __int_as_float(__builtin_amdgcn_readlane(ei, 0));
    const float inv0 = 1.0f / e0;  // r = e_cls / e_blank
    const int* tb = ph_tgt + b * 200;
    float o[4];
#pragma unroll
    for (int k = 0; k < 4; ++k) {
      const int si = lane * 4 + k;
      const int cls = (si < 200) ? tb[si] : 0;
      const float v = __int_as_float(__builtin_amdgcn_ds_bpermute(cls << 2, ei));
      o[k] = (si < 200) ? (v * inv0) : 0.0f;
    }
    *(float4*)(Gph + ((size_t)b * GROWS + t) * 256 + lane * 4) =
        make_float4(o[0], o[1], o[2], o[3]);
    if (lane == 0)
      Lpb_ph[(size_t)b * GROWS + t] = zm - flog2(s);  // log2(pb)
  } else {
    const float4 v = *(const float4*)(err_logits + ((size_t)b * 2000 + t) * 4);
    const float z0 = v.x * LOG2E, z1 = v.y * LOG2E, z2 = v.z * LOG2E,
                z3 = v.w * LOG2E;
    const float m = fmaxf(fmaxf(z0, z1), fmaxf(z2, z3));
    const float e0 = fexp2(z0 - m), e1 = fexp2(z1 - m);
    const float e2 = fexp2(z2 - m), e3 = fexp2(z3 - m);
    const int c1 = err_tgt[b * 50 + (lane < 50 ? lane : 49)];
    const float num = (c1 == 1) ? e1 : (c1 == 2) ? e2 : e3;
    Ger[((size_t)b * GROWS + t) * 64 + lane] = (lane < 50) ? (num / e0) : 0.0f;
    if (lane == 0)
      Lpb_er[(size_t)b * GROWS + t] = (z0 - m) - flog2(e0 + e1 + e2 + e3);
  }
}

// ========================= chain (2-wave split) ============================

template <int P> struct RowP { float v[P]; };

template <int P>
__device__ __forceinline__ RowP<P> lread(const float* p) {
  RowP<P> r;
  if constexpr (P == 2) {
    const float2 a = *(const float2*)p;
    r.v[0] = a.x;
    r.v[1] = a.y;
  } else {
    r.v[0] = *p;
  }
  return r;
}

// returns emax (0 => this wave's half is entirely zero)
template <int P>
__device__ __forceinline__ int bl_renorm(double (&B)[P], double (&L)[P],
                                         int& K) {
  double mm = B[0];
#pragma unroll
  for (int k = 0; k < P; ++k) mm = fmax(fmax(mm, B[k]), L[k]);
  const int ex = (__double2hiint(mm) >> 20) & 0x7ff;
  const int emax = wave_imax(ex);
  if (emax > 0) {
    int d = 1523 - emax;            // pin band max to ~2^500 (R4..R8-proven)
    if (d > 1023) d = 1023;
    if (d < -1022) d = -1022;
    const double sc = __hiloint2double((d + 1023) << 20, 0);
#pragma unroll
    for (int k = 0; k < P; ++k) { B[k] *= sc; L[k] *= sc; }
    K += d;
  }
  return emax;
}

// one recursion step; lane0's cross-boundary L value = bndv (wave A: 0.0)
template <int P>
__device__ __forceinline__ void bl_step(double (&B)[P], double (&L)[P],
                                        const double (&skipm)[P],
                                        const RowP<P>& f, double bndv,
                                        int lane) {
  double Lm1 = dpp_shr1_f64(L[P - 1]);
  if (lane == 0) Lm1 = bndv;
  double nB[P], nL[P];
#pragma unroll
  for (int k = 0; k < P; ++k) {
    const double Lp = (k >= 1) ? L[k - 1] : Lm1;
    nB[k] = B[k] + Lp;
    nL[k] = (double)f.v[k] * fma(skipm[k], Lp, B[k] + L[k]);
  }
#pragma unroll
  for (int k = 0; k < P; ++k) { B[k] = nB[k]; L[k] = nL[k]; }
}

// One block (128 thr = 2 waves) advances one chain.
// Wave A owns pairs 0..64P-1; wave B owns 64P..128P-1 (masked past S).
template <int P, int S, int RSF, bool PH>
__device__ __forceinline__ void split_chain(
    const float* __restrict__ G,    // [GROWS][RSF] expanded ratio rows
    const float* __restrict__ Lpb,  // [GROWS] log2(pb)
    const int* __restrict__ tb, int len, int tl, float* __restrict__ out,
    float* ring, double* bnd, int* kexs, double* saB, double* saL,
    int* kfin) {
  constexpr int SLOT = 16 * RSF;
  constexpr int HALF = 64 * P;                 // pairs per wave
  constexpr bool BDEAD = (HALF >= S + 1);      // wave B half entirely dead
  const int wid = threadIdx.x >> 6;
  const int lane = threadIdx.x & 63;
  const int off = wid ? HALF : 0;

  // spb = sum_{t<len} log2(pb(t))  (wave A)
  float spb = 0.f;
  if (wid == 0) {
    for (int t = lane; t < len; t += 64) spb += Lpb[t];
#pragma unroll
    for (int o = 32; o >= 1; o >>= 1) spb += __shfl_xor(spb, o, 64);
  }

  double skipm[P], B[P], L[P];
#pragma unroll
  for (int k = 0; k < P; ++k) {
    const int s = off + lane * P + k;
    skipm[k] = (s >= 1 && s < S && tb[s] != tb[s - 1]) ? 1.0 : 0.0;
    B[k] = 0.0;
    L[k] = 0.0;
  }
  int K = 0;
  if (wid == 0 && lane == 0) {
    B[0] = 1.0;           // beta-normalized: B[0] = pb/pb = 1
    L[0] = (double)G[0];  // r_{tgt[0]}(t=0)
  }

  const int ntot = (len - 1 + 15) >> 4;  // 16-step windows

  auto issue = [&](int w) {  // wave A only
    const float* rb = G + (size_t)(1 + w * 16) * RSF + lane * (PH ? 4 : 1);
    float* lb = ring + (w & 3) * SLOT;
#pragma unroll
    for (int u = 0; u < 16; ++u) {
      if constexpr (PH) dma16(rb + u * RSF, lb + u * RSF);
      else              dma4(rb + u * RSF, lb + u * RSF);
    }
  };

  if (wid == 0) {
    if (ntot > 0) issue(0);
    if (ntot > 1) issue(1);
  }

  for (int p = 0; p <= ntot; ++p) {
    if (wid == 0) {
      if (p < ntot) {
        if (p + 1 < ntot) wait_vmcnt16();  // slot p resident
        else              wait_vmcnt0();
        bl_renorm<P>(B, L, K);
        if (lane == 0) kexs[p & 1] = K;
        const int cnt = (len - 1 - p * 16 < 16) ? (len - 1 - p * 16) : 16;
        const float* lb = ring + (p & 3) * SLOT + lane * P;
        const int bb = (p & 1) * 16;
        if (cnt == 16) {
          RowP<P> c0 = lread<P>(lb);
          RowP<P> c1 = lread<P>(lb + RSF);
          RowP<P> c2 = lread<P>(lb + 2 * RSF);
          RowP<P> c3 = lread<P>(lb + 3 * RSF);
#pragma unroll
          for (int u = 0; u < 16; ++u) {
            RowP<P> cn = c3;
            if (u + 4 < 16) cn = lread<P>(lb + (u + 4) * RSF);
            if constexpr (!BDEAD)
              if (lane == 63) bnd[bb + u] = L[P - 1];  // pre-step boundary
            bl_step<P>(B, L, skipm, c0, 0.0, lane);
            c0 = c1; c1 = c2; c2 = c3; c3 = cn;
          }
        } else {
          for (int u = 0; u < cnt; ++u) {
            const RowP<P> f = lread<P>(lb + u * RSF);
            if constexpr (!BDEAD)
              if (lane == 63) bnd[bb + u] = L[P - 1];
            bl_step<P>(B, L, skipm, f, 0.0, lane);
          }
        }
        if (p + 2 < ntot) issue(p + 2);
      }
    } else if constexpr (!BDEAD) {
      if (p >= 1) {
        const int w = p - 1;
        const int emaxB = bl_renorm<P>(B, L, K);
        const int kA = kexs[w & 1];
        double adj;
        if (emaxB == 0) {  // half still empty: adopt A's frame
          K = kA;
          adj = 1.0;
        } else {
          int d = K - kA;
          if (d > 1022) d = 1022;
          if (d < -1022) d = -1022;
          adj = __hiloint2double((d + 1023) << 20, 0);
        }
        // boundary values for this window -> lanes 0..15, readlane per step
        double bv = 0.0;
        if (lane < 16) bv = bnd[(w & 1) * 16 + lane];
        const int bvlo = __double2loint(bv), bvhi = __double2hiint(bv);
        const int cnt = (len - 1 - w * 16 < 16) ? (len - 1 - w * 16) : 16;
        const float* lb = ring + (w & 3) * SLOT + HALF + lane * P;
        if (cnt == 16) {
          RowP<P> c0 = lread<P>(lb);
          RowP<P> c1 = lread<P>(lb + RSF);
          RowP<P> c2 = lread<P>(lb + 2 * RSF);
          RowP<P> c3 = lread<P>(lb + 3 * RSF);
#pragma unroll
          for (int u = 0; u < 16; ++u) {
            RowP<P> cn = c3;
            if (u + 4 < 16) cn = lread<P>(lb + (u + 4) * RSF);
            const double bndv =
                __hiloint2double(__builtin_amdgcn_readlane(bvhi, u),
                                 __builtin_amdgcn_readlane(bvlo, u)) * adj;
            bl_step<P>(B, L, skipm, c0, bndv, lane);
            c0 = c1; c1 = c2; c2 = c3; c3 = cn;
          }
        } else {
          for (int u = 0; u < cnt; ++u) {
            const RowP<P> f = lread<P>(lb + u * RSF);
            const double bndv =
                __hiloint2double(__builtin_amdgcn_readlane(bvhi, u),
                                 __builtin_amdgcn_readlane(bvlo, u)) * adj;
            bl_step<P>(B, L, skipm, f, bndv, lane);
          }
        }
      }
    }
    soft_barrier();  // R13: lgkm drain only — DMA prefetch stays in flight
  }

  // ---- readout: alpha[2tl-1] = L[tl-1], alpha[2tl] = B[tl] ----
#pragma unroll
  for (int k = 0; k < P; ++k) {
    saB[off + lane * P + k] = B[k];
    saL[off + lane * P + k] = L[k];
  }
  if (lane == 0) kfin[wid] = K;
  __syncthreads();  // full drain fine here (once)
  if (wid == 0 && lane == 0) {
    const int i1 = tl - 1, i2 = tl;
    const double Lv = saL[i1], Bv = saB[i2];
    const double K1 = (double)((i1 < HALF) ? kfin[0] : kfin[1]);
    const double K2 = (double)((i2 < HALF) ? kfin[0] : kfin[1]);
    const double u1 = log(Lv) - K1 * LN2D;  // log(0) = -inf ok
    const double u2 = log(Bv) - K2 * LN2D;
    const double mx = fmax(u1, u2);
    float loss;
    if (mx < -1e300) {
      loss = 0.f;  // both zero -> +inf loss -> zero_infinity
    } else {
      const double lse = mx + log(exp(u1 - mx) + exp(u2 - mx));
      loss = (float)(-lse - (double)spb * LN2D);
      if (!(loss < 1e29f)) loss = 0.f;
    }
    atomicAdd(out, loss / ((float)tl * 32.0f));
  }
}

__global__ __launch_bounds__(128) void ctc_chains_split_kernel(
    const float* __restrict__ Gph, const float* __restrict__ Ger,
    const float* __restrict__ Lpb_ph, const float* __restrict__ Lpb_er,
    const int* __restrict__ err_tgt, const int* __restrict__ ph_tgt,
    const int* __restrict__ err_il, const int* __restrict__ ph_il,
    const int* __restrict__ err_tl, const int* __restrict__ ph_tl,
    float* __restrict__ out) {
  __shared__ float ring[4 * 16 * 256];  // 64 KB (error uses a prefix)
  __shared__ double bnd[32];            // 2 windows x 16 boundary values
  __shared__ int kexs[2];
  __shared__ double saB[256], saL[256];
  __shared__ int kfin[2];
  const int blk = blockIdx.x;
  if (blk < 32) {
    int len = err_il[blk];
    if (len > 2000) len = 2000;
    split_chain<1, 50, 64, false>(Ger + (size_t)blk * GROWS * 64,
                                  Lpb_er + (size_t)blk * GROWS,
                                  err_tgt + blk * 50, len, err_tl[blk], out,
                                  ring, bnd, kexs, saB, saL, kfin);
  } else {
    const int b = blk - 32;
    int len = ph_il[b];
    if (len > 2000) len = 2000;
    split_chain<2, 200, 256, true>(Gph + (size_t)b * GROWS * 256,
                                   Lpb_ph + (size_t)b * GROWS,
                                   ph_tgt + b * 200, len, ph_tl[b], out, ring,
                                   bnd, kexs, saB, saL, kfin);
  }
}

// ========================= fallback path (R2, proven) ======================

__global__ __launch_bounds__(256) void softmax4_kernel(
    const float* __restrict__ x, float* __restrict__ p, int nrows) {
  int r = blockIdx.x * blockDim.x + threadIdx.x;
  if (r >= nrows) return;
  float4 v = *reinterpret_cast<const float4*>(x + (size_t)r * 4);
  float z0 = v.x * LOG2E, z1 = v.y * LOG2E, z2 = v.z * LOG2E, z3 = v.w * LOG2E;
  float m = fmaxf(fmaxf(z0, z1), fmaxf(z2, z3));
  float e0 = fexp2(z0 - m), e1 = fexp2(z1 - m);
  float e2 = fexp2(z2 - m), e3 = fexp2(z3 - m);
  float inv = 1.0f / (e0 + e1 + e2 + e3);
  float4 o;
  o.x = e0 * inv; o.y = e1 * inv; o.z = e2 * inv; o.w = e3 * inv;
  *reinterpret_cast<float4*>(p + (size_t)r * 4) = o;
}

__global__ __launch_bounds__(256) void softmax64_kernel(
    const float* __restrict__ x, float* __restrict__ p, int nrows) {
  int row = blockIdx.x * 4 + (threadIdx.x >> 6);
  int lane = threadIdx.x & 63;
  if (row >= nrows) return;
  float z = x[(size_t)row * 64 + lane] * LOG2E;
  float m = z;
#pragma unroll
  for (int off = 32; off >= 1; off >>= 1) m = fmaxf(m, __shfl_xor(m, off, 64));
  float e = fexp2(z - m);
  float s = e;
#pragma unroll
  for (int off = 32; off >= 1; off >>= 1) s += __shfl_xor(s, off, 64);
  p[(size_t)row * 64 + lane] = e * (1.0f / s);
}

template <int C, int S, int R>
__device__ __forceinline__ void ctc_chain_lin_fb(
    const float* __restrict__ p_b, const int* __restrict__ tgt_b,
    int len, int tl, float* __restrict__ out, double* sa) {
  constexpr int L = 2 * S + 1;
  const int lane = threadIdx.x;
  int idx[R];
  double skipm[R];
#pragma unroll
  for (int j = 0; j < R; ++j) {
    const int l = lane * R + j;
    int cls = 0;
    bool sk = false;
    if (l & 1) {
      const int s = (l - 1) >> 1;
      const int sc = (s < S) ? s : (S - 1);
      cls = tgt_b[sc];
      if (s >= 1 && s < S) sk = (cls != tgt_b[s - 1]);
    }
    idx[j] = cls * 4;
    skipm[j] = sk ? 1.0 : 0.0;
  }
  double alpha[R];
#pragma unroll
  for (int j = 0; j < R; ++j) {
    const int l = lane * R + j;
    alpha[j] = (l <= 1) ? (double)p_b[idx[j] >> 2] : 0.0;
  }
  int K = 0;
  const int cl = lane & (C - 1);
  float rv = p_b[(size_t)((1 < len - 1) ? 1 : (len - 1)) * C + cl];
  float pf[R];
#pragma unroll
  for (int j = 0; j < R; ++j)
    pf[j] = __int_as_float(__builtin_amdgcn_ds_bpermute(idx[j], __float_as_int(rv)));
  rv = p_b[(size_t)((2 < len - 1) ? 2 : (len - 1)) * C + cl];
  for (int t = 1; t < len; ++t) {
    if ((t & 31) == 0) {
      double m = alpha[0];
#pragma unroll
      for (int j = 1; j < R; ++j) m = fmax(m, alpha[j]);
#pragma unroll
      for (int off = 1; off < 64; off <<= 1) m = fmax(m, __shfl_xor(m, off, 64));
      const long long bits = __double_as_longlong(m);
      const int e = (int)((bits >> 52) & 0x7FF);
      if (e > 0) {
        const double sc = __longlong_as_double((long long)(2046 - e) << 52);
#pragma unroll
        for (int j = 0; j < R; ++j) alpha[j] *= sc;
        K += 1023 - e;
      }
    }
    const int tn = (t + 2 < len) ? (t + 2) : (len - 1);
    const float rvn = p_b[(size_t)tn * C + cl];
    float pfn[R];
#pragma unroll
    for (int j = 0; j < R; ++j)
      pfn[j] = __int_as_float(__builtin_amdgcn_ds_bpermute(idx[j], __float_as_int(rv)));
    double am1 = __shfl_up(alpha[R - 1], 1, 64);
    double am2 = __shfl_up(alpha[R - 2], 1, 64);
    if (lane == 0) { am1 = 0.0; am2 = 0.0; }
    double na[R];
#pragma unroll
    for (int j = 0; j < R; ++j) {
      const double a0 = alpha[j];
      const double a1 = (j >= 1) ? alpha[j - 1] : am1;
      const double a2 = (j >= 2) ? alpha[j - 2] : ((j == 1) ? am1 : am2);
      double s = a0 + a1;
      s = fma(skipm[j], a2, s);
      na[j] = (double)pf[j] * s;
    }
#pragma unroll
    for (int j = 0; j < R; ++j) alpha[j] = na[j];
#pragma unroll
    for (int j = 0; j < R; ++j) pf[j] = pfn[j];
    rv = rvn;
  }
#pragma unroll
  for (int j = 0; j < R; ++j) {
    const int l = lane * R + j;
    if (l < L) sa[l] = alpha[j];
  }
  __syncthreads();
  if (lane == 0) {
    const double a = sa[2 * tl - 1] + sa[2 * tl];
    float loss = (float)((double)K * LN2D - log(a));
    if (!(loss < 1e29f)) loss = 0.0f;
    atomicAdd(out, loss / ((float)tl * 32.0f));
  }
}

__global__ __launch_bounds__(64) void ctc_chains_fb_kernel(
    const float* __restrict__ p_err, const float* __restrict__ p_ph,
    const int* __restrict__ err_tgt, const int* __restrict__ ph_tgt,
    const int* __restrict__ err_il, const int* __restrict__ ph_il,
    const int* __restrict__ err_tl, const int* __restrict__ ph_tl,
    float* __restrict__ out) {
  __shared__ double sa[512];
  const int T = 2000;
  const int blk = blockIdx.x;
  if (blk < 32) {
    const int b = blk;
    int len = err_il[b]; if (len > T) len = T;
    ctc_chain_lin_fb<4, 50, 2>(p_err + (size_t)b * T * 4, err_tgt + b * 50, len,
                               err_tl[b], out, sa);
  } else {
    const int b = blk - 32;
    int len = ph_il[b]; if (len > T) len = T;
    ctc_chain_lin_fb<64, 200, 7>(p_ph + (size_t)b * T * 64, ph_tgt + b * 200,
                                 len, ph_tl[b], out, sa);
  }
}

// ========================= launch ==========================================

extern "C" void kernel_launch(void* const* d_in, const int* in_sizes, int n_in,
                              void* d_out, int out_size, void* d_ws,
                              size_t ws_size, hipStream_t stream) {
  const float* err_logits = (const float*)d_in[0];
  const float* ph_logits  = (const float*)d_in[1];
  const int* err_tgt = (const int*)d_in[2];
  const int* ph_tgt  = (const int*)d_in[3];
  const int* err_il  = (const int*)d_in[4];
  const int* ph_il   = (const int*)d_in[5];
  const int* err_tl  = (const int*)d_in[6];
  const int* ph_tl   = (const int*)d_in[7];
  float* out = (float*)d_out;

  const size_t gph = (size_t)32 * GROWS * 256;  // 66.6 MB
  const size_t ger = (size_t)32 * GROWS * 64;   // 16.6 MB
  const size_t lpb = (size_t)32 * GROWS;        // per task
  const size_t need = (gph + ger + 2 * lpb) * sizeof(float);

  (void)hipMemsetAsync(d_out, 0, sizeof(float), stream);

  if (ws_size >= need) {
    float* Gph = (float*)d_ws;
    float* Ger = Gph + gph;
    float* Lpb_ph = Ger + ger;
    float* Lpb_er = Lpb_ph + lpb;
    dim3 grid(500, 32, 2);
    gather_all_kernel<<<grid, 256, 0, stream>>>(ph_logits, err_logits, ph_tgt,
                                                err_tgt, Gph, Ger, Lpb_ph,
                                                Lpb_er);
    ctc_chains_split_kernel<<<64, 128, 0, stream>>>(Gph, Ger, Lpb_ph, Lpb_er,
                                                    err_tgt, ph_tgt, err_il,
                                                    ph_il, err_tl, ph_tl, out);
  } else {
    const int B = 32, T = 2000;
    const int rows = B * T;
    float* p_err = (float*)d_ws;
    float* p_ph  = p_err + (size_t)rows * 4;
    softmax4_kernel<<<(rows + 255) / 256, 256, 0, stream>>>(err_logits, p_err, rows);
    softmax64_kernel<<<(rows + 3) / 4, 256, 0, stream>>>(ph_logits, p_ph, rows);
    ctc_chains_fb_kernel<<<64, 64, 0, stream>>>(p_err, p_ph, err_tgt, ph_tgt,
                                                err_il, ph_il, err_tl, ph_tl, out);
  }
}